// Round 9
// baseline (348.111 us; speedup 1.0000x reference)
//
#include <hip/hip_runtime.h>
#include <hip/hip_bf16.h>
#include <stdint.h>

#define BB 4
#define NN 16384
#define CC 128
#define MM 2048
#define KNN 16
#define QCAP 512
#define EPS 1e-3f

typedef unsigned int u32;
typedef unsigned short u16;
typedef unsigned long long u64;

// ---- workspace layout (bytes) ----
#define OFF_FEATT   0ull                    // B*N*C f32   = 33554432
#define OFF_PTS4    33554432ull             // B*N float4  =  4194304
#define OFF_WT      37748736ull             // C*C f32     =    65536
#define OFF_KEYS    37814272ull             // B*N u64     =   524288
#define OFF_VEC     38338560ull             // B*C u32     =     2048
#define OFF_IDX     38340608ull             // B*M u32     =    32768
#define OFF_VAL     38373376ull             // B*M f32     =    32768
#define OFF_TMP1    38406144ull             // B*4*2048 u64=   262144
#define OFF_TMP2    38668288ull             // B*2*2048 u64=   131072

// numpy-exact f32 distance: ((pw + nw) - 2*(x*nx + y*ny + z*nz)), no FMA
__device__ __forceinline__ float np_dist(float4 p, float4 nd) {
#pragma clang fp contract(off)
    float dot = ((p.x * nd.x) + (p.y * nd.y)) + (p.z * nd.z);
    float d = (p.w + nd.w) - 2.0f * dot;
    return d;
}

// fast screening value s = -2*dot + p.w  (node-|n|^2 excluded; any rounding ok)
__device__ __forceinline__ float sfast(float4 p, float4 nd) {
    float dot = fmaf(p.x, nd.x, fmaf(p.y, nd.y, p.z * nd.z));
    return fmaf(-2.0f, dot, p.w);
}

__device__ __forceinline__ u32 mono_bits(float d) {
    u32 u = __float_as_uint(d);
    u ^= ((u32)(((int)u) >> 31)) | 0x80000000u;
    return u;
}

// 16th smallest of the 64 per-lane values (each lane-min covers disjoint points)
__device__ __forceinline__ float kth16(float v, int l) {
    float sv = v;
#pragma unroll
    for (int k = 2; k <= 64; k <<= 1) {
#pragma unroll
        for (int j = k >> 1; j > 0; j >>= 1) {
            float pv = __shfl_xor(sv, j);
            bool up = ((l & k) == 0);
            bool tmin = (((l & j) == 0) == up);
            float mn = fminf(sv, pv), mx = fmaxf(sv, pv);
            sv = tmin ? mn : mx;
        }
    }
    return __shfl(sv, 15);
}

// fused prep: pts4 (numpy-exact |p|^2), WT transpose, vecU zero
__global__ void k_prep(const float* __restrict__ coords, const float* __restrict__ W,
                       float4* __restrict__ pts4, float* __restrict__ WT,
                       u32* __restrict__ vecU) {
    int g = blockIdx.x * 256 + threadIdx.x;
    if (g < BB * NN) {
        int b = g >> 14, n = g & (NN - 1);
        const float* cb = coords + (size_t)b * 3 * NN;
        float x = cb[n], y = cb[NN + n], z = cb[2 * NN + n];
        float w;
        {
#pragma clang fp contract(off)
            w = ((x * x) + (y * y)) + (z * z);
        }
        pts4[g] = make_float4(x, y, z, w);
    } else if (g < BB * NN + CC * CC) {
        int i = g - BB * NN;
        int o = i >> 7, c = i & 127;
        WT[c * CC + o] = W[i];
    } else if (g < BB * NN + CC * CC + BB * CC) {
        vecU[g - BB * NN - CC * CC] = 0u;
    }
}

// feat_t[b][n][c] = feats[b][c][n]  (pure transpose, 64x64 LDS tiles)
__global__ void k_transpose(const float* __restrict__ feats, float* __restrict__ feat_t) {
    __shared__ float t[64][65];
    int bx = blockIdx.x;
    int b = bx >> 9; int rem = bx & 511; int nb = rem >> 1; int cb2 = rem & 1;
    int n0 = nb * 64, c0 = cb2 * 64;
    int l = threadIdx.x & 63, r0 = threadIdx.x >> 6;
    const float* fb = feats + (size_t)b * CC * NN;
#pragma unroll
    for (int p = 0; p < 16; ++p) {
        int r = r0 + p * 4;
        t[r][l] = fb[(size_t)(c0 + r) * NN + n0 + l];
    }
    __syncthreads();
    float* ob = feat_t + (size_t)b * NN * CC;
#pragma unroll
    for (int p = 0; p < 16; ++p) {
        int r = r0 + p * 4;
        ob[(size_t)(n0 + r) * CC + c0 + l] = t[l][r];
    }
}

// vector[b][o] = max_n relu(sum_c W[o][c]*Z[c][n] + bias[o])
// lane = n (coalesced feats reads); thread owns o-quarter acc[32];
// W rows via wave-uniform float4 loads (L1-hot), distance-1 double-buffered.
// Summation order identical to prior rounds (bias + ascending-c fmaf chain).
__global__ __launch_bounds__(256) void k_vec(const float* __restrict__ feats,
        const float* __restrict__ WT, const float* __restrict__ bias, u32* __restrict__ vecU) {
    int bx = blockIdx.x;                 // B * (N/64)
    int b = bx >> 8; int n0 = (bx & 255) * 64;
    int tid = threadIdx.x, l = tid & 63;
    int q = __builtin_amdgcn_readfirstlane(tid >> 6);   // o-quarter 0..3
    int o0 = q * 32;
    const float* fb = feats + (size_t)b * CC * NN + n0 + l;
    const float4* wt = (const float4*)(WT + o0);        // row c at wt + c*32
    float acc[32];
#pragma unroll
    for (int oi = 0; oi < 32; ++oi) acc[oi] = bias[o0 + oi];
    // prefetch c=0
    float4 wb0 = wt[0], wb1 = wt[1], wb2 = wt[2], wb3 = wt[3];
    float4 wb4 = wt[4], wb5 = wt[5], wb6 = wt[6], wb7 = wt[7];
    float zb = fb[0];
#pragma unroll 1
    for (int c = 0; c < CC; ++c) {
        float4 w0 = wb0, w1 = wb1, w2 = wb2, w3 = wb3;
        float4 w4 = wb4, w5 = wb5, w6 = wb6, w7 = wb7;
        float zc = zb;
        if (c + 1 < CC) {                 // prefetch next c while FMAs run
            const float4* wn = wt + (c + 1) * 32;
            wb0 = wn[0]; wb1 = wn[1]; wb2 = wn[2]; wb3 = wn[3];
            wb4 = wn[4]; wb5 = wn[5]; wb6 = wn[6]; wb7 = wn[7];
            zb = fb[(size_t)(c + 1) * NN];
        }
        acc[0]  = fmaf(w0.x, zc, acc[0]);  acc[1]  = fmaf(w0.y, zc, acc[1]);
        acc[2]  = fmaf(w0.z, zc, acc[2]);  acc[3]  = fmaf(w0.w, zc, acc[3]);
        acc[4]  = fmaf(w1.x, zc, acc[4]);  acc[5]  = fmaf(w1.y, zc, acc[5]);
        acc[6]  = fmaf(w1.z, zc, acc[6]);  acc[7]  = fmaf(w1.w, zc, acc[7]);
        acc[8]  = fmaf(w2.x, zc, acc[8]);  acc[9]  = fmaf(w2.y, zc, acc[9]);
        acc[10] = fmaf(w2.z, zc, acc[10]); acc[11] = fmaf(w2.w, zc, acc[11]);
        acc[12] = fmaf(w3.x, zc, acc[12]); acc[13] = fmaf(w3.y, zc, acc[13]);
        acc[14] = fmaf(w3.z, zc, acc[14]); acc[15] = fmaf(w3.w, zc, acc[15]);
        acc[16] = fmaf(w4.x, zc, acc[16]); acc[17] = fmaf(w4.y, zc, acc[17]);
        acc[18] = fmaf(w4.z, zc, acc[18]); acc[19] = fmaf(w4.w, zc, acc[19]);
        acc[20] = fmaf(w5.x, zc, acc[20]); acc[21] = fmaf(w5.y, zc, acc[21]);
        acc[22] = fmaf(w5.z, zc, acc[22]); acc[23] = fmaf(w5.w, zc, acc[23]);
        acc[24] = fmaf(w6.x, zc, acc[24]); acc[25] = fmaf(w6.y, zc, acc[25]);
        acc[26] = fmaf(w6.z, zc, acc[26]); acc[27] = fmaf(w6.w, zc, acc[27]);
        acc[28] = fmaf(w7.x, zc, acc[28]); acc[29] = fmaf(w7.y, zc, acc[29]);
        acc[30] = fmaf(w7.z, zc, acc[30]); acc[31] = fmaf(w7.w, zc, acc[31]);
    }
#pragma unroll
    for (int oi = 0; oi < 32; ++oi) {
        float rv = acc[oi] > 0.0f ? acc[oi] : 0.0f;   // relu, +0.0 guaranteed
#pragma unroll
        for (int s = 32; s; s >>= 1) rv = fmaxf(rv, __shfl_xor(rv, s));
        if (l == 0) atomicMax(vecU + b * CC + o0 + oi, __float_as_uint(rv));
    }
}

// keys[b][n] = (mono(sigmoid(sum_c feats*vector)) << 32) | (~n)
__global__ void k_scores(const float* __restrict__ feats, const float* __restrict__ vecF,
                         u64* __restrict__ keys) {
    int i = blockIdx.x * 256 + threadIdx.x;    // < B*N
    int b = i >> 14, n = i & (NN - 1);
    const float* fb = feats + (size_t)b * CC * NN + n;
    const float* vb = vecF + b * CC;
    float wsum = 0.f;
#pragma unroll 8
    for (int c = 0; c < CC; ++c) wsum = fmaf(fb[(size_t)c * NN], vb[c], wsum);
    float s = 1.0f / (1.0f + expf(-wsum));     // scores >= 0 -> bits monotonic
    u32 mono = __float_as_uint(s);
    keys[i] = ((u64)mono << 32) | (u64)(0xFFFFFFFFu - (u32)n);
}

// sort one 2048-key chunk descending, in place (32 blocks, 1024 thr)
__global__ __launch_bounds__(1024) void k_sortchunk(u64* __restrict__ keys) {
    __shared__ u64 sk[2048];
    int b = blockIdx.x >> 3, c = blockIdx.x & 7;
    int tid = threadIdx.x;
    u64* src = keys + (size_t)b * NN + c * 2048;
    sk[tid] = src[tid];
    sk[tid + 1024] = src[tid + 1024];
    for (int size = 2; size <= 2048; size <<= 1) {
        for (int stride = size >> 1; stride > 0; stride >>= 1) {
            __syncthreads();
            int t = tid;
            int i = (t << 1) - (t & (stride - 1));
            int j = i + stride;
            u64 a = sk[i], cc = sk[j];
            bool up = ((i & size) == 0);
            if ((a < cc) == up) { sk[i] = cc; sk[j] = a; }
        }
    }
    __syncthreads();
    src[tid] = sk[tid];
    src[tid + 1024] = sk[tid + 1024];
}

// merge two descending 2048-lists -> top-2048 (descending)
__global__ __launch_bounds__(512) void k_mergetop(const u64* __restrict__ in,
        u64* __restrict__ outp, int lg /* log2(pairs per batch) */) {
    __shared__ u64 mk[4096];
    int b = blockIdx.x >> lg, pr = blockIdx.x & ((1 << lg) - 1);
    int tid = threadIdx.x;
    const u64* s0 = in + ((size_t)((b << lg) + pr) * 2) * 2048;
    const u64* s1 = s0 + 2048;
    for (int t = tid; t < 2048; t += 512) { mk[t] = s0[t]; mk[2048 + t] = s1[2047 - t]; }
    __syncthreads();
    for (int t = tid; t < 2048; t += 512) {
        u64 a = mk[t], c = mk[t + 2048];
        if (a < c) { mk[t] = c; mk[t + 2048] = a; }
    }
    for (int stride = 1024; stride > 0; stride >>= 1) {
        __syncthreads();
        for (int t = tid; t < 1024; t += 512) {
            int i = (t << 1) - (t & (stride - 1));
            int j = i + stride;
            u64 a = mk[i], c = mk[j];
            if (a < c) { mk[i] = c; mk[j] = a; }
        }
    }
    __syncthreads();
    u64* dst = outp + (size_t)((b << lg) + pr) * 2048;
    for (int t = tid; t < 2048; t += 512) dst[t] = mk[t];
}

// final merge -> idxA/valA
__global__ __launch_bounds__(512) void k_mergefinal(const u64* __restrict__ in,
        u32* __restrict__ idxA, float* __restrict__ valA) {
    __shared__ u64 mk[4096];
    int b = blockIdx.x, tid = threadIdx.x;
    const u64* s0 = in + (size_t)(b * 2) * 2048;
    const u64* s1 = s0 + 2048;
    for (int t = tid; t < 2048; t += 512) { mk[t] = s0[t]; mk[2048 + t] = s1[2047 - t]; }
    __syncthreads();
    for (int t = tid; t < 2048; t += 512) {
        u64 a = mk[t], c = mk[t + 2048];
        if (a < c) { mk[t] = c; mk[t + 2048] = a; }
    }
    for (int stride = 1024; stride > 0; stride >>= 1) {
        __syncthreads();
        for (int t = tid; t < 1024; t += 512) {
            int i = (t << 1) - (t & (stride - 1));
            int j = i + stride;
            u64 a = mk[i], c = mk[j];
            if (a < c) { mk[i] = c; mk[j] = a; }
        }
    }
    __syncthreads();
    for (int t = tid; t < 2048; t += 512) {
        u64 k = mk[t];
        idxA[b * MM + t] = 0xFFFFFFFFu - (u32)(k & 0xFFFFFFFFull);
        valA[b * MM + t] = __uint_as_float((u32)(k >> 32));
    }
}

// outputs 0,1 and first half of output 2
__global__ void k_gather(const float4* __restrict__ pts4, const float* __restrict__ feat_t,
        const u32* __restrict__ idxA, const float* __restrict__ valA, float* __restrict__ out) {
    int g = blockIdx.x * 256 + threadIdx.x;    // < B*M
    int b = g >> 11, i = g & (MM - 1);
    u32 n = idxA[g];
    float v = valA[g];
    float4 p = pts4[(b << 14) + (int)n];
    float* o0 = out + (size_t)b * 3 * MM + i;
    o0[0] = p.x; o0[MM] = p.y; o0[2 * MM] = p.z;
    float* o1 = o0 + 24576;
    o1[0] = p.x * v; o1[MM] = p.y * v; o1[2 * MM] = p.z * v;
    const float4* ft = (const float4*)(feat_t + ((size_t)(b << 14) + n) * CC);
    float* o2 = out + 49152 + ((size_t)b * 256) * MM + i;
#pragma unroll 8
    for (int q = 0; q < 32; ++q) {
        float4 f = ft[q];
        o2[(size_t)(4 * q + 0) * MM] = f.x * v;
        o2[(size_t)(4 * q + 1) * MM] = f.y * v;
        o2[(size_t)(4 * q + 2) * MM] = f.z * v;
        o2[(size_t)(4 * q + 3) * MM] = f.w * v;
    }
}

// kNN(k=16) + channel-max aggregation -> second half of output 2
// 4 nodes/block (1/wave); u16 LDS queues; 20.5KB LDS -> 7 blocks/CU; grid 2048.
__global__ __launch_bounds__(256, 7) void k_knn(const float4* __restrict__ pts4,
        const float* __restrict__ feat_t, const u32* __restrict__ idxA, float* __restrict__ out) {
    __shared__ float4 ptsS[1024];
    __shared__ u16 qS[4][QCAP];
    __shared__ float4 nodeS[4];
    int bx = blockIdx.x;
    int b = bx >> 9, mblk = bx & 511;
    int tid = threadIdx.x, l = tid & 63;
    const float4* pb = pts4 + (b << 14);
    if (tid < 4) nodeS[tid] = pb[idxA[b * MM + mblk * 4 + tid]];
#pragma unroll
    for (int j = 0; j < 4; ++j) ptsS[tid + 256 * j] = pb[tid + 256 * j];
    __syncthreads();
    int w = __builtin_amdgcn_readfirstlane(tid >> 6);
    float4 nd = nodeS[w];
    // pass 1: per-lane min over 2048-pt sample -> 16th-smallest -> threshold
    float lm = 3.0e38f;
#pragma unroll 4
    for (int j = 0; j < 16; ++j) lm = fminf(lm, sfast(ptsS[l + 64 * j], nd));
    __syncthreads();
#pragma unroll
    for (int j = 0; j < 4; ++j) ptsS[tid + 256 * j] = pb[1024 + tid + 256 * j];
    __syncthreads();
#pragma unroll 4
    for (int j = 0; j < 16; ++j) lm = fminf(lm, sfast(ptsS[l + 64 * j], nd));
    float T = kth16(lm, l) + 2.0f * EPS;
    // pass 2: sweep all 16 chunks, compact survivor u16 indices per node
    int qc = 0;
    for (int ch = 0; ch < 16; ++ch) {
        __syncthreads();
#pragma unroll
        for (int j = 0; j < 4; ++j) ptsS[tid + 256 * j] = pb[ch * 1024 + tid + 256 * j];
        __syncthreads();
        for (int j = 0; j < 16; ++j) {
            float4 p = ptsS[l + 64 * j];
            float dt = fmaf(p.x, nd.x, fmaf(p.y, nd.y, p.z * nd.z));
            float s = fmaf(-2.0f, dt, p.w);
            bool pred = (s <= T);
            u64 bal = __ballot(pred);
            if (bal) {
                if (pred) {
                    int off = __builtin_amdgcn_mbcnt_hi((u32)(bal >> 32),
                              __builtin_amdgcn_mbcnt_lo((u32)bal, 0));
                    int slot = qc + off;
                    if (slot < QCAP) qS[w][slot] = (u16)(ch * 1024 + l + 64 * j);
                }
                qc += (int)__popcll(bal);
            }
        }
    }
    // pass 3: exact keys (numpy-exact d, index tie-break), 16x wave-argmin + feat max
    int cnt = qc < QCAP ? qc : QCAP;
    u64 regk[QCAP / 64];
#pragma unroll
    for (int s = 0; s < QCAP / 64; ++s) {
        u64 kk = ~0ull;
        if ((s << 6) < cnt) {
            int pos = (s << 6) + l;
            if (pos < cnt) {
                u32 n = qS[w][pos];
                float d = np_dist(pb[n], nd);
                kk = ((u64)mono_bits(d) << 32) | (u64)n;
            }
        }
        regk[s] = kk;
    }
    float mx0 = -3.0e38f, mx1 = -3.0e38f;
    for (int it = 0; it < KNN; ++it) {
        u64 mykey = ~0ull;
#pragma unroll
        for (int s = 0; s < QCAP / 64; ++s)
            if ((s << 6) < cnt) mykey = regk[s] < mykey ? regk[s] : mykey;
        u64 r = mykey;
#pragma unroll
        for (int j = 32; j > 0; j >>= 1) {
            u64 o = __shfl_xor(r, j);
            r = o < r ? o : r;
        }
#pragma unroll
        for (int s = 0; s < QCAP / 64; ++s)
            if ((s << 6) < cnt) { if (regk[s] == r) regk[s] = ~0ull; }
        if (r != ~0ull) {
            u32 nj = (u32)(r & 0xFFFFFFFFull);
            const float2 f = *(const float2*)(feat_t + ((size_t)(b << 14) + nj) * CC + (l << 1));
            mx0 = fmaxf(mx0, f.x);
            mx1 = fmaxf(mx1, f.y);
        }
    }
    int m = mblk * 4 + w;
    size_t ob = 49152 + ((size_t)(b * 256 + 128 + 2 * l)) * MM + m;
    out[ob] = mx0;
    out[ob + MM] = mx1;
}

extern "C" void kernel_launch(void* const* d_in, const int* in_sizes, int n_in,
                              void* d_out, int out_size, void* d_ws, size_t ws_size,
                              hipStream_t stream) {
    const float* coords = (const float*)d_in[0];
    const float* feats  = (const float*)d_in[1];
    const float* W      = (const float*)d_in[2];
    const float* bias   = (const float*)d_in[3];
    char* ws = (char*)d_ws;
    float*  feat_t = (float*)(ws + OFF_FEATT);
    float4* pts4   = (float4*)(ws + OFF_PTS4);
    float*  WT     = (float*)(ws + OFF_WT);
    u64*    keys   = (u64*)(ws + OFF_KEYS);
    u32*    vecU   = (u32*)(ws + OFF_VEC);
    u32*    idxA   = (u32*)(ws + OFF_IDX);
    float*  valA   = (float*)(ws + OFF_VAL);
    u64*    tmp1   = (u64*)(ws + OFF_TMP1);
    u64*    tmp2   = (u64*)(ws + OFF_TMP2);
    float*  out    = (float*)d_out;

    int prepN = BB * NN + CC * CC + BB * CC;
    k_prep     <<<(prepN + 255) / 256, 256, 0, stream>>>(coords, W, pts4, WT, vecU);
    k_vec      <<<BB * (NN / 64), 256, 0, stream>>>(feats, WT, bias, vecU);
    k_transpose<<<BB * (NN / 64) * (CC / 64), 256, 0, stream>>>(feats, feat_t);
    k_scores   <<<BB * NN / 256, 256, 0, stream>>>(feats, (const float*)vecU, keys);
    k_sortchunk<<<BB * 8, 1024, 0, stream>>>(keys);
    k_mergetop <<<BB * 4, 512, 0, stream>>>(keys, tmp1, 2);
    k_mergetop <<<BB * 2, 512, 0, stream>>>(tmp1, tmp2, 1);
    k_mergefinal<<<BB, 512, 0, stream>>>(tmp2, idxA, valA);
    k_gather   <<<BB * MM / 256, 256, 0, stream>>>(pts4, feat_t, idxA, valA, out);
    k_knn      <<<BB * (MM / 4), 256, 0, stream>>>(pts4, feat_t, idxA, out);
}

// Round 10
// 302.784 us; speedup vs baseline: 1.1497x; 1.1497x over previous
//
#include <hip/hip_runtime.h>
#include <hip/hip_bf16.h>
#include <stdint.h>

#define BB 4
#define NN 16384
#define CC 128
#define MM 2048
#define KNN 16
#define QCAP 512
#define EPS 1e-3f

typedef unsigned int u32;
typedef unsigned short u16;
typedef unsigned long long u64;

// ---- workspace layout (bytes) ----
#define OFF_FEATT   0ull                    // B*N*C f32   = 33554432
#define OFF_PTS4    33554432ull             // B*N float4  =  4194304
#define OFF_WT      37748736ull             // C*C f32     =    65536
#define OFF_KEYS    37814272ull             // B*N u64     =   524288
#define OFF_VEC     38338560ull             // B*C u32     =     2048
#define OFF_IDX     38340608ull             // B*M u32     =    32768
#define OFF_VAL     38373376ull             // B*M f32     =    32768
#define OFF_TMP1    38406144ull             // B*4*2048 u64=   262144
#define OFF_TMP2    38668288ull             // B*2*2048 u64=   131072

// numpy-exact f32 distance: ((pw + nw) - 2*(x*nx + y*ny + z*nz)), no FMA
__device__ __forceinline__ float np_dist(float4 p, float4 nd) {
#pragma clang fp contract(off)
    float dot = ((p.x * nd.x) + (p.y * nd.y)) + (p.z * nd.z);
    float d = (p.w + nd.w) - 2.0f * dot;
    return d;
}

// fast screening value s = -2*dot + p.w  (node-|n|^2 excluded; any rounding ok)
__device__ __forceinline__ float sfast(float4 p, float4 nd) {
    float dot = fmaf(p.x, nd.x, fmaf(p.y, nd.y, p.z * nd.z));
    return fmaf(-2.0f, dot, p.w);
}

__device__ __forceinline__ u32 mono_bits(float d) {
    u32 u = __float_as_uint(d);
    u ^= ((u32)(((int)u) >> 31)) | 0x80000000u;
    return u;
}

// 16th smallest of the 64 per-lane values (each lane-min covers disjoint points)
__device__ __forceinline__ float kth16(float v, int l) {
    float sv = v;
#pragma unroll
    for (int k = 2; k <= 64; k <<= 1) {
#pragma unroll
        for (int j = k >> 1; j > 0; j >>= 1) {
            float pv = __shfl_xor(sv, j);
            bool up = ((l & k) == 0);
            bool tmin = (((l & j) == 0) == up);
            float mn = fminf(sv, pv), mx = fmaxf(sv, pv);
            sv = tmin ? mn : mx;
        }
    }
    return __shfl(sv, 15);
}

// fused prep: pts4 (numpy-exact |p|^2), WT transpose, vecU zero
__global__ void k_prep(const float* __restrict__ coords, const float* __restrict__ W,
                       float4* __restrict__ pts4, float* __restrict__ WT,
                       u32* __restrict__ vecU) {
    int g = blockIdx.x * 256 + threadIdx.x;
    if (g < BB * NN) {
        int b = g >> 14, n = g & (NN - 1);
        const float* cb = coords + (size_t)b * 3 * NN;
        float x = cb[n], y = cb[NN + n], z = cb[2 * NN + n];
        float w;
        {
#pragma clang fp contract(off)
            w = ((x * x) + (y * y)) + (z * z);
        }
        pts4[g] = make_float4(x, y, z, w);
    } else if (g < BB * NN + CC * CC) {
        int i = g - BB * NN;
        int o = i >> 7, c = i & 127;
        WT[c * CC + o] = W[i];
    } else if (g < BB * NN + CC * CC + BB * CC) {
        vecU[g - BB * NN - CC * CC] = 0u;
    }
}

// feat_t[b][n][c] = feats[b][c][n]  (pure transpose, 64x64 LDS tiles)
__global__ void k_transpose(const float* __restrict__ feats, float* __restrict__ feat_t) {
    __shared__ float t[64][65];
    int bx = blockIdx.x;
    int b = bx >> 9; int rem = bx & 511; int nb = rem >> 1; int cb2 = rem & 1;
    int n0 = nb * 64, c0 = cb2 * 64;
    int l = threadIdx.x & 63, r0 = threadIdx.x >> 6;
    const float* fb = feats + (size_t)b * CC * NN;
#pragma unroll
    for (int p = 0; p < 16; ++p) {
        int r = r0 + p * 4;
        t[r][l] = fb[(size_t)(c0 + r) * NN + n0 + l];
    }
    __syncthreads();
    float* ob = feat_t + (size_t)b * NN * CC;
#pragma unroll
    for (int p = 0; p < 16; ++p) {
        int r = r0 + p * 4;
        ob[(size_t)(n0 + r) * CC + c0 + l] = t[l][r];
    }
}

// vector[b][o] = max_n relu(sum_c W[o][c]*Z[c][n] + bias[o])
// 8 waves/block; wave w owns o-slice [w*16, w*16+16); lane = n.
// z tile (128c x 64n) in LDS; W row-slice (16 f32, 64B) via uniform load.
// acc[16] only -> ~50 VGPR, no spill (cap 85 via launch_bounds(512,6)).
// Summation order identical to all passing rounds (bias + ascending-c fmaf).
__global__ __launch_bounds__(512, 6) void k_vec(const float* __restrict__ feats,
        const float* __restrict__ WT, const float* __restrict__ bias, u32* __restrict__ vecU) {
    __shared__ float zl[CC][64];
    int bx = blockIdx.x;                 // B * (N/64) = 1024
    int b = bx >> 8; int n0 = (bx & 255) * 64;
    int tid = threadIdx.x, l = tid & 63;
    int w = __builtin_amdgcn_readfirstlane(tid >> 6);   // 0..7
    const float* fb = feats + (size_t)b * CC * NN + n0;
    for (int r = w; r < CC; r += 8)
        zl[r][l] = fb[(size_t)r * NN + l];
    __syncthreads();
    int o0 = w * 16;
    const float* wt = WT + o0;
    float acc[16];
#pragma unroll
    for (int oi = 0; oi < 16; ++oi) acc[oi] = bias[o0 + oi];
#pragma unroll 2
    for (int c = 0; c < CC; ++c) {
        float zc = zl[c][l];
        const float4* wr = (const float4*)(wt + c * CC);   // wave-uniform 64B
        float4 w0 = wr[0], w1 = wr[1], w2 = wr[2], w3 = wr[3];
        acc[0]  = fmaf(w0.x, zc, acc[0]);  acc[1]  = fmaf(w0.y, zc, acc[1]);
        acc[2]  = fmaf(w0.z, zc, acc[2]);  acc[3]  = fmaf(w0.w, zc, acc[3]);
        acc[4]  = fmaf(w1.x, zc, acc[4]);  acc[5]  = fmaf(w1.y, zc, acc[5]);
        acc[6]  = fmaf(w1.z, zc, acc[6]);  acc[7]  = fmaf(w1.w, zc, acc[7]);
        acc[8]  = fmaf(w2.x, zc, acc[8]);  acc[9]  = fmaf(w2.y, zc, acc[9]);
        acc[10] = fmaf(w2.z, zc, acc[10]); acc[11] = fmaf(w2.w, zc, acc[11]);
        acc[12] = fmaf(w3.x, zc, acc[12]); acc[13] = fmaf(w3.y, zc, acc[13]);
        acc[14] = fmaf(w3.z, zc, acc[14]); acc[15] = fmaf(w3.w, zc, acc[15]);
    }
#pragma unroll
    for (int oi = 0; oi < 16; ++oi) {
        float rv = acc[oi] > 0.0f ? acc[oi] : 0.0f;   // relu, +0.0 guaranteed
#pragma unroll
        for (int s = 32; s; s >>= 1) rv = fmaxf(rv, __shfl_xor(rv, s));
        if (l == 0) atomicMax(vecU + b * CC + o0 + oi, __float_as_uint(rv));
    }
}

// keys[b][n] = (mono(sigmoid(sum_c feats*vector)) << 32) | (~n)
__global__ void k_scores(const float* __restrict__ feats, const float* __restrict__ vecF,
                         u64* __restrict__ keys) {
    int i = blockIdx.x * 256 + threadIdx.x;    // < B*N
    int b = i >> 14, n = i & (NN - 1);
    const float* fb = feats + (size_t)b * CC * NN + n;
    const float* vb = vecF + b * CC;
    float wsum = 0.f;
#pragma unroll 8
    for (int c = 0; c < CC; ++c) wsum = fmaf(fb[(size_t)c * NN], vb[c], wsum);
    float s = 1.0f / (1.0f + expf(-wsum));     // scores >= 0 -> bits monotonic
    u32 mono = __float_as_uint(s);
    keys[i] = ((u64)mono << 32) | (u64)(0xFFFFFFFFu - (u32)n);
}

// sort one 2048-key chunk descending, in place (32 blocks, 1024 thr)
__global__ __launch_bounds__(1024) void k_sortchunk(u64* __restrict__ keys) {
    __shared__ u64 sk[2048];
    int b = blockIdx.x >> 3, c = blockIdx.x & 7;
    int tid = threadIdx.x;
    u64* src = keys + (size_t)b * NN + c * 2048;
    sk[tid] = src[tid];
    sk[tid + 1024] = src[tid + 1024];
    for (int size = 2; size <= 2048; size <<= 1) {
        for (int stride = size >> 1; stride > 0; stride >>= 1) {
            __syncthreads();
            int t = tid;
            int i = (t << 1) - (t & (stride - 1));
            int j = i + stride;
            u64 a = sk[i], cc = sk[j];
            bool up = ((i & size) == 0);
            if ((a < cc) == up) { sk[i] = cc; sk[j] = a; }
        }
    }
    __syncthreads();
    src[tid] = sk[tid];
    src[tid + 1024] = sk[tid + 1024];
}

// merge two descending 2048-lists -> top-2048 (descending)
__global__ __launch_bounds__(512) void k_mergetop(const u64* __restrict__ in,
        u64* __restrict__ outp, int lg /* log2(pairs per batch) */) {
    __shared__ u64 mk[4096];
    int b = blockIdx.x >> lg, pr = blockIdx.x & ((1 << lg) - 1);
    int tid = threadIdx.x;
    const u64* s0 = in + ((size_t)((b << lg) + pr) * 2) * 2048;
    const u64* s1 = s0 + 2048;
    for (int t = tid; t < 2048; t += 512) { mk[t] = s0[t]; mk[2048 + t] = s1[2047 - t]; }
    __syncthreads();
    for (int t = tid; t < 2048; t += 512) {
        u64 a = mk[t], c = mk[t + 2048];
        if (a < c) { mk[t] = c; mk[t + 2048] = a; }
    }
    for (int stride = 1024; stride > 0; stride >>= 1) {
        __syncthreads();
        for (int t = tid; t < 1024; t += 512) {
            int i = (t << 1) - (t & (stride - 1));
            int j = i + stride;
            u64 a = mk[i], c = mk[j];
            if (a < c) { mk[i] = c; mk[j] = a; }
        }
    }
    __syncthreads();
    u64* dst = outp + (size_t)((b << lg) + pr) * 2048;
    for (int t = tid; t < 2048; t += 512) dst[t] = mk[t];
}

// final merge -> idxA/valA
__global__ __launch_bounds__(512) void k_mergefinal(const u64* __restrict__ in,
        u32* __restrict__ idxA, float* __restrict__ valA) {
    __shared__ u64 mk[4096];
    int b = blockIdx.x, tid = threadIdx.x;
    const u64* s0 = in + (size_t)(b * 2) * 2048;
    const u64* s1 = s0 + 2048;
    for (int t = tid; t < 2048; t += 512) { mk[t] = s0[t]; mk[2048 + t] = s1[2047 - t]; }
    __syncthreads();
    for (int t = tid; t < 2048; t += 512) {
        u64 a = mk[t], c = mk[t + 2048];
        if (a < c) { mk[t] = c; mk[t + 2048] = a; }
    }
    for (int stride = 1024; stride > 0; stride >>= 1) {
        __syncthreads();
        for (int t = tid; t < 1024; t += 512) {
            int i = (t << 1) - (t & (stride - 1));
            int j = i + stride;
            u64 a = mk[i], c = mk[j];
            if (a < c) { mk[i] = c; mk[j] = a; }
        }
    }
    __syncthreads();
    for (int t = tid; t < 2048; t += 512) {
        u64 k = mk[t];
        idxA[b * MM + t] = 0xFFFFFFFFu - (u32)(k & 0xFFFFFFFFull);
        valA[b * MM + t] = __uint_as_float((u32)(k >> 32));
    }
}

// outputs 0,1 and first half of output 2
__global__ void k_gather(const float4* __restrict__ pts4, const float* __restrict__ feat_t,
        const u32* __restrict__ idxA, const float* __restrict__ valA, float* __restrict__ out) {
    int g = blockIdx.x * 256 + threadIdx.x;    // < B*M
    int b = g >> 11, i = g & (MM - 1);
    u32 n = idxA[g];
    float v = valA[g];
    float4 p = pts4[(b << 14) + (int)n];
    float* o0 = out + (size_t)b * 3 * MM + i;
    o0[0] = p.x; o0[MM] = p.y; o0[2 * MM] = p.z;
    float* o1 = o0 + 24576;
    o1[0] = p.x * v; o1[MM] = p.y * v; o1[2 * MM] = p.z * v;
    const float4* ft = (const float4*)(feat_t + ((size_t)(b << 14) + n) * CC);
    float* o2 = out + 49152 + ((size_t)b * 256) * MM + i;
#pragma unroll 8
    for (int q = 0; q < 32; ++q) {
        float4 f = ft[q];
        o2[(size_t)(4 * q + 0) * MM] = f.x * v;
        o2[(size_t)(4 * q + 1) * MM] = f.y * v;
        o2[(size_t)(4 * q + 2) * MM] = f.z * v;
        o2[(size_t)(4 * q + 3) * MM] = f.w * v;
    }
}

// kNN(k=16) + channel-max aggregation -> second half of output 2
// 4 nodes/block (1/wave); u16 LDS queues; 20.5KB LDS -> 7 blocks/CU; grid 2048.
__global__ __launch_bounds__(256, 7) void k_knn(const float4* __restrict__ pts4,
        const float* __restrict__ feat_t, const u32* __restrict__ idxA, float* __restrict__ out) {
    __shared__ float4 ptsS[1024];
    __shared__ u16 qS[4][QCAP];
    __shared__ float4 nodeS[4];
    int bx = blockIdx.x;
    int b = bx >> 9, mblk = bx & 511;
    int tid = threadIdx.x, l = tid & 63;
    const float4* pb = pts4 + (b << 14);
    if (tid < 4) nodeS[tid] = pb[idxA[b * MM + mblk * 4 + tid]];
#pragma unroll
    for (int j = 0; j < 4; ++j) ptsS[tid + 256 * j] = pb[tid + 256 * j];
    __syncthreads();
    int w = __builtin_amdgcn_readfirstlane(tid >> 6);
    float4 nd = nodeS[w];
    // pass 1: per-lane min over 2048-pt sample -> 16th-smallest -> threshold
    float lm = 3.0e38f;
#pragma unroll 4
    for (int j = 0; j < 16; ++j) lm = fminf(lm, sfast(ptsS[l + 64 * j], nd));
    __syncthreads();
#pragma unroll
    for (int j = 0; j < 4; ++j) ptsS[tid + 256 * j] = pb[1024 + tid + 256 * j];
    __syncthreads();
#pragma unroll 4
    for (int j = 0; j < 16; ++j) lm = fminf(lm, sfast(ptsS[l + 64 * j], nd));
    float T = kth16(lm, l) + 2.0f * EPS;
    // pass 2: sweep all 16 chunks, compact survivor u16 indices per node
    int qc = 0;
    for (int ch = 0; ch < 16; ++ch) {
        __syncthreads();
#pragma unroll
        for (int j = 0; j < 4; ++j) ptsS[tid + 256 * j] = pb[ch * 1024 + tid + 256 * j];
        __syncthreads();
        for (int j = 0; j < 16; ++j) {
            float4 p = ptsS[l + 64 * j];
            float dt = fmaf(p.x, nd.x, fmaf(p.y, nd.y, p.z * nd.z));
            float s = fmaf(-2.0f, dt, p.w);
            bool pred = (s <= T);
            u64 bal = __ballot(pred);
            if (bal) {
                if (pred) {
                    int off = __builtin_amdgcn_mbcnt_hi((u32)(bal >> 32),
                              __builtin_amdgcn_mbcnt_lo((u32)bal, 0));
                    int slot = qc + off;
                    if (slot < QCAP) qS[w][slot] = (u16)(ch * 1024 + l + 64 * j);
                }
                qc += (int)__popcll(bal);
            }
        }
    }
    // pass 3: exact keys (numpy-exact d, index tie-break), 16x wave-argmin + feat max
    int cnt = qc < QCAP ? qc : QCAP;
    u64 regk[QCAP / 64];
#pragma unroll
    for (int s = 0; s < QCAP / 64; ++s) {
        u64 kk = ~0ull;
        if ((s << 6) < cnt) {
            int pos = (s << 6) + l;
            if (pos < cnt) {
                u32 n = qS[w][pos];
                float d = np_dist(pb[n], nd);
                kk = ((u64)mono_bits(d) << 32) | (u64)n;
            }
        }
        regk[s] = kk;
    }
    float mx0 = -3.0e38f, mx1 = -3.0e38f;
    for (int it = 0; it < KNN; ++it) {
        u64 mykey = ~0ull;
#pragma unroll
        for (int s = 0; s < QCAP / 64; ++s)
            if ((s << 6) < cnt) mykey = regk[s] < mykey ? regk[s] : mykey;
        u64 r = mykey;
#pragma unroll
        for (int j = 32; j > 0; j >>= 1) {
            u64 o = __shfl_xor(r, j);
            r = o < r ? o : r;
        }
#pragma unroll
        for (int s = 0; s < QCAP / 64; ++s)
            if ((s << 6) < cnt) { if (regk[s] == r) regk[s] = ~0ull; }
        if (r != ~0ull) {
            u32 nj = (u32)(r & 0xFFFFFFFFull);
            const float2 f = *(const float2*)(feat_t + ((size_t)(b << 14) + nj) * CC + (l << 1));
            mx0 = fmaxf(mx0, f.x);
            mx1 = fmaxf(mx1, f.y);
        }
    }
    int m = mblk * 4 + w;
    size_t ob = 49152 + ((size_t)(b * 256 + 128 + 2 * l)) * MM + m;
    out[ob] = mx0;
    out[ob + MM] = mx1;
}

extern "C" void kernel_launch(void* const* d_in, const int* in_sizes, int n_in,
                              void* d_out, int out_size, void* d_ws, size_t ws_size,
                              hipStream_t stream) {
    const float* coords = (const float*)d_in[0];
    const float* feats  = (const float*)d_in[1];
    const float* W      = (const float*)d_in[2];
    const float* bias   = (const float*)d_in[3];
    char* ws = (char*)d_ws;
    float*  feat_t = (float*)(ws + OFF_FEATT);
    float4* pts4   = (float4*)(ws + OFF_PTS4);
    float*  WT     = (float*)(ws + OFF_WT);
    u64*    keys   = (u64*)(ws + OFF_KEYS);
    u32*    vecU   = (u32*)(ws + OFF_VEC);
    u32*    idxA   = (u32*)(ws + OFF_IDX);
    float*  valA   = (float*)(ws + OFF_VAL);
    u64*    tmp1   = (u64*)(ws + OFF_TMP1);
    u64*    tmp2   = (u64*)(ws + OFF_TMP2);
    float*  out    = (float*)d_out;

    int prepN = BB * NN + CC * CC + BB * CC;
    k_prep     <<<(prepN + 255) / 256, 256, 0, stream>>>(coords, W, pts4, WT, vecU);
    k_vec      <<<BB * (NN / 64), 512, 0, stream>>>(feats, WT, bias, vecU);
    k_transpose<<<BB * (NN / 64) * (CC / 64), 256, 0, stream>>>(feats, feat_t);
    k_scores   <<<BB * NN / 256, 256, 0, stream>>>(feats, (const float*)vecU, keys);
    k_sortchunk<<<BB * 8, 1024, 0, stream>>>(keys);
    k_mergetop <<<BB * 4, 512, 0, stream>>>(keys, tmp1, 2);
    k_mergetop <<<BB * 2, 512, 0, stream>>>(tmp1, tmp2, 1);
    k_mergefinal<<<BB, 512, 0, stream>>>(tmp2, idxA, valA);
    k_gather   <<<BB * MM / 256, 256, 0, stream>>>(pts4, feat_t, idxA, valA, out);
    k_knn      <<<BB * (MM / 4), 256, 0, stream>>>(pts4, feat_t, idxA, out);
}

// Round 11
// 239.010 us; speedup vs baseline: 1.4565x; 1.2668x over previous
//
#include <hip/hip_runtime.h>
#include <hip/hip_bf16.h>
#include <stdint.h>

#define BB 4
#define NN 16384
#define CC 128
#define MM 2048
#define KNN 16
#define QCAP 512
#define EPS 1e-3f

typedef unsigned int u32;
typedef unsigned short u16;
typedef unsigned long long u64;

// ---- workspace layout (bytes) ----
#define OFF_FEATT   0ull                    // B*N*C f32   = 33554432
#define OFF_PTS4    33554432ull             // B*N float4  =  4194304
#define OFF_WT      37748736ull             // C*C f32     =    65536
#define OFF_KEYS    37814272ull             // B*N u64     =   524288
#define OFF_VEC     38338560ull             // B*C u32     =     2048
#define OFF_IDX     38340608ull             // B*M u32     =    32768
#define OFF_VAL     38373376ull             // B*M f32     =    32768
#define OFF_TMP1    38406144ull             // B*4*2048 u64=   262144
#define OFF_TMP2    38668288ull             // B*2*2048 u64=   131072

// numpy-exact f32 distance: ((pw + nw) - 2*(x*nx + y*ny + z*nz)), no FMA
__device__ __forceinline__ float np_dist(float4 p, float4 nd) {
#pragma clang fp contract(off)
    float dot = ((p.x * nd.x) + (p.y * nd.y)) + (p.z * nd.z);
    float d = (p.w + nd.w) - 2.0f * dot;
    return d;
}

// fast screening value s = -2*dot + p.w  (node-|n|^2 excluded; any rounding ok)
__device__ __forceinline__ float sfast(float4 p, float4 nd) {
    float dot = fmaf(p.x, nd.x, fmaf(p.y, nd.y, p.z * nd.z));
    return fmaf(-2.0f, dot, p.w);
}

__device__ __forceinline__ u32 mono_bits(float d) {
    u32 u = __float_as_uint(d);
    u ^= ((u32)(((int)u) >> 31)) | 0x80000000u;
    return u;
}

// 16th smallest of the 64 per-lane values (each lane-min covers disjoint points)
__device__ __forceinline__ float kth16(float v, int l) {
    float sv = v;
#pragma unroll
    for (int k = 2; k <= 64; k <<= 1) {
#pragma unroll
        for (int j = k >> 1; j > 0; j >>= 1) {
            float pv = __shfl_xor(sv, j);
            bool up = ((l & k) == 0);
            bool tmin = (((l & j) == 0) == up);
            float mn = fminf(sv, pv), mx = fmaxf(sv, pv);
            sv = tmin ? mn : mx;
        }
    }
    return __shfl(sv, 15);
}

// fused prep: pts4 (numpy-exact |p|^2), WT transpose, vecU zero
__global__ void k_prep(const float* __restrict__ coords, const float* __restrict__ W,
                       float4* __restrict__ pts4, float* __restrict__ WT,
                       u32* __restrict__ vecU) {
    int g = blockIdx.x * 256 + threadIdx.x;
    if (g < BB * NN) {
        int b = g >> 14, n = g & (NN - 1);
        const float* cb = coords + (size_t)b * 3 * NN;
        float x = cb[n], y = cb[NN + n], z = cb[2 * NN + n];
        float w;
        {
#pragma clang fp contract(off)
            w = ((x * x) + (y * y)) + (z * z);
        }
        pts4[g] = make_float4(x, y, z, w);
    } else if (g < BB * NN + CC * CC) {
        int i = g - BB * NN;
        int o = i >> 7, c = i & 127;
        WT[c * CC + o] = W[i];
    } else if (g < BB * NN + CC * CC + BB * CC) {
        vecU[g - BB * NN - CC * CC] = 0u;
    }
}

// feat_t[b][n][c] = feats[b][c][n]  (pure transpose, 64x64 LDS tiles)
__global__ void k_transpose(const float* __restrict__ feats, float* __restrict__ feat_t) {
    __shared__ float t[64][65];
    int bx = blockIdx.x;
    int b = bx >> 9; int rem = bx & 511; int nb = rem >> 1; int cb2 = rem & 1;
    int n0 = nb * 64, c0 = cb2 * 64;
    int l = threadIdx.x & 63, r0 = threadIdx.x >> 6;
    const float* fb = feats + (size_t)b * CC * NN;
#pragma unroll
    for (int p = 0; p < 16; ++p) {
        int r = r0 + p * 4;
        t[r][l] = fb[(size_t)(c0 + r) * NN + n0 + l];
    }
    __syncthreads();
    float* ob = feat_t + (size_t)b * NN * CC;
#pragma unroll
    for (int p = 0; p < 16; ++p) {
        int r = r0 + p * 4;
        ob[(size_t)(n0 + r) * CC + c0 + l] = t[l][r];
    }
}

// vector[b][o] = max_n relu(sum_c W[o][c]*Z[c][n] + bias[o])
// Block = 4 waves, owns o-half (64 o's); W-half staged in LDS (32 KB, on-chip).
// Wave w -> 16 o's; lane l -> 4 n's (acc[16][4], static). Per c:
// 4 uniform ds_read_b128 (broadcast) + 1 coalesced z dwordx4 (prefetched) + 64 FMA.
// Summation order identical to all passing rounds (bias + ascending-c fmaf).
__global__ __launch_bounds__(256, 4) void k_vec(const float* __restrict__ feats,
        const float* __restrict__ WT, const float* __restrict__ bias, u32* __restrict__ vecU) {
    __shared__ float Wl[CC * 64];        // [c][64 o-half]
    int bx = blockIdx.x;                 // 512: b(4) x ntile(64) x oh(2)
    int oh = bx & 1;
    int ntile = (bx >> 1) & 63;
    int b = bx >> 7;
    int n0 = ntile * 256;
    int tid = threadIdx.x, l = tid & 63;
    int w = __builtin_amdgcn_readfirstlane(tid >> 6);   // 0..3
    // stage W-half: Wl[c*64 + o'] = WT[c*128 + oh*64 + o']
    for (int i = tid; i < CC * 64; i += 256) {
        int c = i >> 6, op = i & 63;
        Wl[i] = WT[c * CC + oh * 64 + op];
    }
    __syncthreads();
    int o0 = w * 16;                     // within half
    const float* zb = feats + (size_t)b * CC * NN + n0 + 4 * l;
    float bo[16];
#pragma unroll
    for (int oi = 0; oi < 16; ++oi) bo[oi] = bias[oh * 64 + o0 + oi];
    float acc0[16], acc1[16], acc2[16], acc3[16];
#pragma unroll
    for (int oi = 0; oi < 16; ++oi) { acc0[oi] = bo[oi]; acc1[oi] = bo[oi]; acc2[oi] = bo[oi]; acc3[oi] = bo[oi]; }
    float4 zpre = *(const float4*)zb;    // prefetch c=0
#pragma unroll 2
    for (int c = 0; c < CC; ++c) {
        float4 z = zpre;
        if (c + 1 < CC) zpre = *(const float4*)(zb + (size_t)(c + 1) * NN);
        const float* wr = Wl + c * 64 + o0;          // wave-uniform LDS
        float4 w0 = *(const float4*)(wr);
        float4 w1 = *(const float4*)(wr + 4);
        float4 w2 = *(const float4*)(wr + 8);
        float4 w3 = *(const float4*)(wr + 12);
        float wv[16] = {w0.x, w0.y, w0.z, w0.w, w1.x, w1.y, w1.z, w1.w,
                        w2.x, w2.y, w2.z, w2.w, w3.x, w3.y, w3.z, w3.w};
#pragma unroll
        for (int oi = 0; oi < 16; ++oi) {
            acc0[oi] = fmaf(wv[oi], z.x, acc0[oi]);
            acc1[oi] = fmaf(wv[oi], z.y, acc1[oi]);
            acc2[oi] = fmaf(wv[oi], z.z, acc2[oi]);
            acc3[oi] = fmaf(wv[oi], z.w, acc3[oi]);
        }
    }
#pragma unroll
    for (int oi = 0; oi < 16; ++oi) {
        float r0 = acc0[oi] > 0.0f ? acc0[oi] : 0.0f;   // relu, +0.0 guaranteed
        float r1 = acc1[oi] > 0.0f ? acc1[oi] : 0.0f;
        float r2 = acc2[oi] > 0.0f ? acc2[oi] : 0.0f;
        float r3 = acc3[oi] > 0.0f ? acc3[oi] : 0.0f;
        float rv = fmaxf(fmaxf(r0, r1), fmaxf(r2, r3));
#pragma unroll
        for (int s = 32; s; s >>= 1) rv = fmaxf(rv, __shfl_xor(rv, s));
        if (l == 0) atomicMax(vecU + b * CC + oh * 64 + o0 + oi, __float_as_uint(rv));
    }
}

// keys[b][n] = (mono(sigmoid(sum_c feats*vector)) << 32) | (~n)
__global__ void k_scores(const float* __restrict__ feats, const float* __restrict__ vecF,
                         u64* __restrict__ keys) {
    int i = blockIdx.x * 256 + threadIdx.x;    // < B*N
    int b = i >> 14, n = i & (NN - 1);
    const float* fb = feats + (size_t)b * CC * NN + n;
    const float* vb = vecF + b * CC;
    float wsum = 0.f;
#pragma unroll 8
    for (int c = 0; c < CC; ++c) wsum = fmaf(fb[(size_t)c * NN], vb[c], wsum);
    float s = 1.0f / (1.0f + expf(-wsum));     // scores >= 0 -> bits monotonic
    u32 mono = __float_as_uint(s);
    keys[i] = ((u64)mono << 32) | (u64)(0xFFFFFFFFu - (u32)n);
}

// sort one 2048-key chunk descending, in place (32 blocks, 1024 thr)
__global__ __launch_bounds__(1024) void k_sortchunk(u64* __restrict__ keys) {
    __shared__ u64 sk[2048];
    int b = blockIdx.x >> 3, c = blockIdx.x & 7;
    int tid = threadIdx.x;
    u64* src = keys + (size_t)b * NN + c * 2048;
    sk[tid] = src[tid];
    sk[tid + 1024] = src[tid + 1024];
    for (int size = 2; size <= 2048; size <<= 1) {
        for (int stride = size >> 1; stride > 0; stride >>= 1) {
            __syncthreads();
            int t = tid;
            int i = (t << 1) - (t & (stride - 1));
            int j = i + stride;
            u64 a = sk[i], cc = sk[j];
            bool up = ((i & size) == 0);
            if ((a < cc) == up) { sk[i] = cc; sk[j] = a; }
        }
    }
    __syncthreads();
    src[tid] = sk[tid];
    src[tid + 1024] = sk[tid + 1024];
}

// merge two descending 2048-lists -> top-2048 (descending)
__global__ __launch_bounds__(512) void k_mergetop(const u64* __restrict__ in,
        u64* __restrict__ outp, int lg /* log2(pairs per batch) */) {
    __shared__ u64 mk[4096];
    int b = blockIdx.x >> lg, pr = blockIdx.x & ((1 << lg) - 1);
    int tid = threadIdx.x;
    const u64* s0 = in + ((size_t)((b << lg) + pr) * 2) * 2048;
    const u64* s1 = s0 + 2048;
    for (int t = tid; t < 2048; t += 512) { mk[t] = s0[t]; mk[2048 + t] = s1[2047 - t]; }
    __syncthreads();
    for (int t = tid; t < 2048; t += 512) {
        u64 a = mk[t], c = mk[t + 2048];
        if (a < c) { mk[t] = c; mk[t + 2048] = a; }
    }
    for (int stride = 1024; stride > 0; stride >>= 1) {
        __syncthreads();
        for (int t = tid; t < 1024; t += 512) {
            int i = (t << 1) - (t & (stride - 1));
            int j = i + stride;
            u64 a = mk[i], c = mk[j];
            if (a < c) { mk[i] = c; mk[j] = a; }
        }
    }
    __syncthreads();
    u64* dst = outp + (size_t)((b << lg) + pr) * 2048;
    for (int t = tid; t < 2048; t += 512) dst[t] = mk[t];
}

// final merge -> idxA/valA
__global__ __launch_bounds__(512) void k_mergefinal(const u64* __restrict__ in,
        u32* __restrict__ idxA, float* __restrict__ valA) {
    __shared__ u64 mk[4096];
    int b = blockIdx.x, tid = threadIdx.x;
    const u64* s0 = in + (size_t)(b * 2) * 2048;
    const u64* s1 = s0 + 2048;
    for (int t = tid; t < 2048; t += 512) { mk[t] = s0[t]; mk[2048 + t] = s1[2047 - t]; }
    __syncthreads();
    for (int t = tid; t < 2048; t += 512) {
        u64 a = mk[t], c = mk[t + 2048];
        if (a < c) { mk[t] = c; mk[t + 2048] = a; }
    }
    for (int stride = 1024; stride > 0; stride >>= 1) {
        __syncthreads();
        for (int t = tid; t < 1024; t += 512) {
            int i = (t << 1) - (t & (stride - 1));
            int j = i + stride;
            u64 a = mk[i], c = mk[j];
            if (a < c) { mk[i] = c; mk[j] = a; }
        }
    }
    __syncthreads();
    for (int t = tid; t < 2048; t += 512) {
        u64 k = mk[t];
        idxA[b * MM + t] = 0xFFFFFFFFu - (u32)(k & 0xFFFFFFFFull);
        valA[b * MM + t] = __uint_as_float((u32)(k >> 32));
    }
}

// outputs 0,1 and first half of output 2
__global__ void k_gather(const float4* __restrict__ pts4, const float* __restrict__ feat_t,
        const u32* __restrict__ idxA, const float* __restrict__ valA, float* __restrict__ out) {
    int g = blockIdx.x * 256 + threadIdx.x;    // < B*M
    int b = g >> 11, i = g & (MM - 1);
    u32 n = idxA[g];
    float v = valA[g];
    float4 p = pts4[(b << 14) + (int)n];
    float* o0 = out + (size_t)b * 3 * MM + i;
    o0[0] = p.x; o0[MM] = p.y; o0[2 * MM] = p.z;
    float* o1 = o0 + 24576;
    o1[0] = p.x * v; o1[MM] = p.y * v; o1[2 * MM] = p.z * v;
    const float4* ft = (const float4*)(feat_t + ((size_t)(b << 14) + n) * CC);
    float* o2 = out + 49152 + ((size_t)b * 256) * MM + i;
#pragma unroll 8
    for (int q = 0; q < 32; ++q) {
        float4 f = ft[q];
        o2[(size_t)(4 * q + 0) * MM] = f.x * v;
        o2[(size_t)(4 * q + 1) * MM] = f.y * v;
        o2[(size_t)(4 * q + 2) * MM] = f.z * v;
        o2[(size_t)(4 * q + 3) * MM] = f.w * v;
    }
}

// kNN(k=16) + channel-max aggregation -> second half of output 2
// 4 nodes/block (1/wave); u16 LDS queues; 20.5KB LDS -> 7 blocks/CU; grid 2048.
__global__ __launch_bounds__(256, 7) void k_knn(const float4* __restrict__ pts4,
        const float* __restrict__ feat_t, const u32* __restrict__ idxA, float* __restrict__ out) {
    __shared__ float4 ptsS[1024];
    __shared__ u16 qS[4][QCAP];
    __shared__ float4 nodeS[4];
    int bx = blockIdx.x;
    int b = bx >> 9, mblk = bx & 511;
    int tid = threadIdx.x, l = tid & 63;
    const float4* pb = pts4 + (b << 14);
    if (tid < 4) nodeS[tid] = pb[idxA[b * MM + mblk * 4 + tid]];
#pragma unroll
    for (int j = 0; j < 4; ++j) ptsS[tid + 256 * j] = pb[tid + 256 * j];
    __syncthreads();
    int w = __builtin_amdgcn_readfirstlane(tid >> 6);
    float4 nd = nodeS[w];
    // pass 1: per-lane min over 2048-pt sample -> 16th-smallest -> threshold
    float lm = 3.0e38f;
#pragma unroll 4
    for (int j = 0; j < 16; ++j) lm = fminf(lm, sfast(ptsS[l + 64 * j], nd));
    __syncthreads();
#pragma unroll
    for (int j = 0; j < 4; ++j) ptsS[tid + 256 * j] = pb[1024 + tid + 256 * j];
    __syncthreads();
#pragma unroll 4
    for (int j = 0; j < 16; ++j) lm = fminf(lm, sfast(ptsS[l + 64 * j], nd));
    float T = kth16(lm, l) + 2.0f * EPS;
    // pass 2: sweep all 16 chunks, compact survivor u16 indices per node
    int qc = 0;
    for (int ch = 0; ch < 16; ++ch) {
        __syncthreads();
#pragma unroll
        for (int j = 0; j < 4; ++j) ptsS[tid + 256 * j] = pb[ch * 1024 + tid + 256 * j];
        __syncthreads();
        for (int j = 0; j < 16; ++j) {
            float4 p = ptsS[l + 64 * j];
            float dt = fmaf(p.x, nd.x, fmaf(p.y, nd.y, p.z * nd.z));
            float s = fmaf(-2.0f, dt, p.w);
            bool pred = (s <= T);
            u64 bal = __ballot(pred);
            if (bal) {
                if (pred) {
                    int off = __builtin_amdgcn_mbcnt_hi((u32)(bal >> 32),
                              __builtin_amdgcn_mbcnt_lo((u32)bal, 0));
                    int slot = qc + off;
                    if (slot < QCAP) qS[w][slot] = (u16)(ch * 1024 + l + 64 * j);
                }
                qc += (int)__popcll(bal);
            }
        }
    }
    // pass 3: exact keys (numpy-exact d, index tie-break), 16x wave-argmin + feat max
    int cnt = qc < QCAP ? qc : QCAP;
    u64 regk[QCAP / 64];
#pragma unroll
    for (int s = 0; s < QCAP / 64; ++s) {
        u64 kk = ~0ull;
        if ((s << 6) < cnt) {
            int pos = (s << 6) + l;
            if (pos < cnt) {
                u32 n = qS[w][pos];
                float d = np_dist(pb[n], nd);
                kk = ((u64)mono_bits(d) << 32) | (u64)n;
            }
        }
        regk[s] = kk;
    }
    float mx0 = -3.0e38f, mx1 = -3.0e38f;
    for (int it = 0; it < KNN; ++it) {
        u64 mykey = ~0ull;
#pragma unroll
        for (int s = 0; s < QCAP / 64; ++s)
            if ((s << 6) < cnt) mykey = regk[s] < mykey ? regk[s] : mykey;
        u64 r = mykey;
#pragma unroll
        for (int j = 32; j > 0; j >>= 1) {
            u64 o = __shfl_xor(r, j);
            r = o < r ? o : r;
        }
#pragma unroll
        for (int s = 0; s < QCAP / 64; ++s)
            if ((s << 6) < cnt) { if (regk[s] == r) regk[s] = ~0ull; }
        if (r != ~0ull) {
            u32 nj = (u32)(r & 0xFFFFFFFFull);
            const float2 f = *(const float2*)(feat_t + ((size_t)(b << 14) + nj) * CC + (l << 1));
            mx0 = fmaxf(mx0, f.x);
            mx1 = fmaxf(mx1, f.y);
        }
    }
    int m = mblk * 4 + w;
    size_t ob = 49152 + ((size_t)(b * 256 + 128 + 2 * l)) * MM + m;
    out[ob] = mx0;
    out[ob + MM] = mx1;
}

extern "C" void kernel_launch(void* const* d_in, const int* in_sizes, int n_in,
                              void* d_out, int out_size, void* d_ws, size_t ws_size,
                              hipStream_t stream) {
    const float* coords = (const float*)d_in[0];
    const float* feats  = (const float*)d_in[1];
    const float* W      = (const float*)d_in[2];
    const float* bias   = (const float*)d_in[3];
    char* ws = (char*)d_ws;
    float*  feat_t = (float*)(ws + OFF_FEATT);
    float4* pts4   = (float4*)(ws + OFF_PTS4);
    float*  WT     = (float*)(ws + OFF_WT);
    u64*    keys   = (u64*)(ws + OFF_KEYS);
    u32*    vecU   = (u32*)(ws + OFF_VEC);
    u32*    idxA   = (u32*)(ws + OFF_IDX);
    float*  valA   = (float*)(ws + OFF_VAL);
    u64*    tmp1   = (u64*)(ws + OFF_TMP1);
    u64*    tmp2   = (u64*)(ws + OFF_TMP2);
    float*  out    = (float*)d_out;

    int prepN = BB * NN + CC * CC + BB * CC;
    k_prep     <<<(prepN + 255) / 256, 256, 0, stream>>>(coords, W, pts4, WT, vecU);
    k_vec      <<<512, 256, 0, stream>>>(feats, WT, bias, vecU);
    k_transpose<<<BB * (NN / 64) * (CC / 64), 256, 0, stream>>>(feats, feat_t);
    k_scores   <<<BB * NN / 256, 256, 0, stream>>>(feats, (const float*)vecU, keys);
    k_sortchunk<<<BB * 8, 1024, 0, stream>>>(keys);
    k_mergetop <<<BB * 4, 512, 0, stream>>>(keys, tmp1, 2);
    k_mergetop <<<BB * 2, 512, 0, stream>>>(tmp1, tmp2, 1);
    k_mergefinal<<<BB, 512, 0, stream>>>(tmp2, idxA, valA);
    k_gather   <<<BB * MM / 256, 256, 0, stream>>>(pts4, feat_t, idxA, valA, out);
    k_knn      <<<BB * (MM / 4), 256, 0, stream>>>(pts4, feat_t, idxA, out);
}